// Round 2
// baseline (11204.350 us; speedup 1.0000x reference)
//
#include <hip/hip_runtime.h>

#define B_ROWS 65536

typedef __attribute__((ext_vector_type(8))) __bf16 bf16x8;
typedef __attribute__((ext_vector_type(8))) _Float16 f16x8;
typedef __attribute__((ext_vector_type(4))) float f32x4;
typedef __attribute__((ext_vector_type(8))) unsigned short u16x8;

__device__ __forceinline__ unsigned short f2bf(float f) {
  unsigned int u = __float_as_uint(f);
  u += 0x7fffu + ((u >> 16) & 1u);   // RNE
  return (unsigned short)(u >> 16);
}

__device__ __forceinline__ float elu_f(float v) {
  return v > 0.f ? v : __expf(v) - 1.f;
}

__device__ __forceinline__ void async_ld16(const void* g, void* l) {
  __builtin_amdgcn_global_load_lds(
      (const __attribute__((address_space(1))) void*)g,
      (__attribute__((address_space(3))) void*)l, 16, 0, 0);
}

// ---------------- fused gating MLP (f16 MFMA, f32 acc) + z->bf16 convert ----
#define GP 136  // padded LDS row stride in f16 (272 B -> 2-way banks = free)

__global__ __launch_bounds__(256) void gating_mfma(
    const float* __restrict__ z, const int* __restrict__ idx,
    const float* __restrict__ Wg1, const float* __restrict__ bg1,
    const float* __restrict__ Wg2, const float* __restrict__ bg2,
    const float* __restrict__ Wg3, const float* __restrict__ bg3,
    float* __restrict__ wq, unsigned short* __restrict__ zb) {
  __shared__ _Float16 Ab[128 * GP];   // activations [row][k]
  __shared__ _Float16 Wb[128 * GP];   // W^T [n][k]
  __shared__ int idx_l[128];

  const int tid = threadIdx.x;
  const int lane = tid & 63, wave = tid >> 6;
  const int wr = wave >> 1, wc = wave & 1;
  const int lhi = lane >> 4, llo = lane & 15;
  const size_t row0 = (size_t)blockIdx.x * 128;

  if (tid < 128) idx_l[tid] = idx[tid];
  for (int i = tid; i < 16384; i += 256) {
    const int k = i >> 7, n = i & 127;
    Wb[n * GP + k] = (_Float16)Wg1[i];
  }
  {
    const float* zr = z + row0 * 512;
    unsigned short* zo = zb + row0 * 512;
    for (int i = tid; i < 8192; i += 256) {
      const size_t off = (size_t)i * 8;
      float4 a = *(const float4*)(zr + off);
      float4 b = *(const float4*)(zr + off + 4);
      u16x8 r;
      r[0] = f2bf(a.x); r[1] = f2bf(a.y); r[2] = f2bf(a.z); r[3] = f2bf(a.w);
      r[4] = f2bf(b.x); r[5] = f2bf(b.y); r[6] = f2bf(b.z); r[7] = f2bf(b.w);
      *(u16x8*)(zo + off) = r;
    }
  }
  __syncthreads();
  for (int i = tid; i < 16384; i += 256) {
    const int r = i >> 7, c = i & 127;
    Ab[r * GP + c] = (_Float16)z[(row0 + r) * 512 + idx_l[c]];
  }
  __syncthreads();

  const f32x4 vzero = {0.f, 0.f, 0.f, 0.f};

  // ---- layer 1 ----
  f32x4 C[4][4];
#pragma unroll
  for (int i = 0; i < 4; i++)
#pragma unroll
    for (int j = 0; j < 4; j++) C[i][j] = vzero;
#pragma unroll
  for (int ks = 0; ks < 4; ks++) {
    f16x8 av[4], bv[4];
#pragma unroll
    for (int fm = 0; fm < 4; fm++)
      av[fm] = *(const f16x8*)&Ab[(wr * 64 + fm * 16 + llo) * GP + ks * 32 + lhi * 8];
#pragma unroll
    for (int fn = 0; fn < 4; fn++)
      bv[fn] = *(const f16x8*)&Wb[(wc * 64 + fn * 16 + llo) * GP + ks * 32 + lhi * 8];
#pragma unroll
    for (int fm = 0; fm < 4; fm++)
#pragma unroll
      for (int fn = 0; fn < 4; fn++)
        C[fm][fn] = __builtin_amdgcn_mfma_f32_16x16x32_f16(av[fm], bv[fn], C[fm][fn], 0, 0, 0);
  }
  __syncthreads();
#pragma unroll
  for (int fm = 0; fm < 4; fm++)
#pragma unroll
    for (int fn = 0; fn < 4; fn++) {
      const int col = wc * 64 + fn * 16 + llo;
      const float bb = bg1[col];
#pragma unroll
      for (int r = 0; r < 4; r++) {
        const int row = wr * 64 + fm * 16 + lhi * 4 + r;
        Ab[row * GP + col] = (_Float16)elu_f(C[fm][fn][r] + bb);
      }
    }
  for (int i = tid; i < 16384; i += 256) {
    const int k = i >> 7, n = i & 127;
    Wb[n * GP + k] = (_Float16)Wg2[i];
  }
  __syncthreads();

  // ---- layer 2 ----
#pragma unroll
  for (int i = 0; i < 4; i++)
#pragma unroll
    for (int j = 0; j < 4; j++) C[i][j] = vzero;
#pragma unroll
  for (int ks = 0; ks < 4; ks++) {
    f16x8 av[4], bv[4];
#pragma unroll
    for (int fm = 0; fm < 4; fm++)
      av[fm] = *(const f16x8*)&Ab[(wr * 64 + fm * 16 + llo) * GP + ks * 32 + lhi * 8];
#pragma unroll
    for (int fn = 0; fn < 4; fn++)
      bv[fn] = *(const f16x8*)&Wb[(wc * 64 + fn * 16 + llo) * GP + ks * 32 + lhi * 8];
#pragma unroll
    for (int fm = 0; fm < 4; fm++)
#pragma unroll
      for (int fn = 0; fn < 4; fn++)
        C[fm][fn] = __builtin_amdgcn_mfma_f32_16x16x32_f16(av[fm], bv[fn], C[fm][fn], 0, 0, 0);
  }
  __syncthreads();
#pragma unroll
  for (int fm = 0; fm < 4; fm++)
#pragma unroll
    for (int fn = 0; fn < 4; fn++) {
      const int col = wc * 64 + fn * 16 + llo;
      const float bb = bg2[col];
#pragma unroll
      for (int r = 0; r < 4; r++) {
        const int row = wr * 64 + fm * 16 + lhi * 4 + r;
        Ab[row * GP + col] = (_Float16)elu_f(C[fm][fn][r] + bb);
      }
    }
  for (int i = tid; i < 2048; i += 256) {
    const int k = i >> 4, n = i & 15;
    Wb[n * GP + k] = (n < 8) ? (_Float16)Wg3[k * 8 + n] : (_Float16)0.f;
  }
  __syncthreads();

  // ---- layer 3 ----
  f32x4 C3[4];
#pragma unroll
  for (int i = 0; i < 4; i++) C3[i] = vzero;
#pragma unroll
  for (int ks = 0; ks < 4; ks++) {
    f16x8 av[4];
#pragma unroll
    for (int fm = 0; fm < 4; fm++)
      av[fm] = *(const f16x8*)&Ab[(wr * 64 + fm * 16 + llo) * GP + ks * 32 + lhi * 8];
    const f16x8 bv = *(const f16x8*)&Wb[llo * GP + ks * 32 + lhi * 8];
#pragma unroll
    for (int fm = 0; fm < 4; fm++)
      C3[fm] = __builtin_amdgcn_mfma_f32_16x16x32_f16(av[fm], bv, C3[fm], 0, 0, 0);
  }
  if (wc == 0 && llo < 8) {
    const float bb = bg3[llo];
#pragma unroll
    for (int fm = 0; fm < 4; fm++)
#pragma unroll
      for (int r = 0; r < 4; r++) {
        const size_t row = row0 + wr * 64 + fm * 16 + lhi * 4 + r;
        wq[row * 8 + llo] = C3[fm][r] + bb;
      }
  }
}

// ---------------- W[e][i][o] f32 -> Wt[e][o][i] bf16 (B^T layout) ----------
__global__ __launch_bounds__(256) void transpose_w(
    const float* __restrict__ W1, const float* __restrict__ W2,
    const float* __restrict__ W3, unsigned short* __restrict__ Wt) {
  __shared__ float t[32][33];
  const int le = blockIdx.z;  // layer*8 + e, 0..23
  const float* W = (le < 8) ? W1 : (le < 16) ? W2 : W3;
  const size_t eoff = (size_t)(le & 7) * 262144;
  unsigned short* O = Wt + (size_t)le * 262144;
  const int i0 = blockIdx.y * 32, o0 = blockIdx.x * 32;
  const int tx = threadIdx.x & 31, ty = threadIdx.x >> 5;
#pragma unroll
  for (int s = 0; s < 4; s++)
    t[ty + s * 8][tx] = W[eoff + (size_t)(i0 + ty + s * 8) * 512 + o0 + tx];
  __syncthreads();
#pragma unroll
  for (int s = 0; s < 4; s++)
    O[(size_t)(o0 + ty + s * 8) * 512 + i0 + tx] = f2bf(t[tx][ty + s * 8]);
}

// ---------------- soft-MoE expert layer: out = sum_e w_e*(X@W_e + b_e) -----
// BM=256 x BN=128 tile, BK=64, 512 threads (8 waves, 4Mx2N, each 64x64).
// LOOP-INTERCHANGED: kt outer, e inner.  C = sum_kt sum_e w_e*(A_kt @ B_e,kt)
//   - A-tile staged once per kt (32KB, double-buffered), its 8 MFMA frags
//     held in 32 VGPRs for all 8 expert steps -> A global traffic cut 8x and
//     steady-state LDS reads halved (8 b128/wave/step instead of 16).
//   - B tiles (16KB) triple-buffered, prefetch depth 2, counted vmcnt:
//     steady vmcnt(2); vmcnt(6) on the two steps after the A-issue (e==4).
//   - setprio(1) around each 32-MFMA cluster; per-step f32 combine C += w*acc.
// LDS: A 2x32768 @0, B 3x16384 @65536 -> 114688 B (+w/bias 12KB).
template <bool ELU, bool OUTBF>
__global__ __launch_bounds__(512, 2) void expert_layer(
    const unsigned short* __restrict__ X,   // 65536 x 512 bf16
    const unsigned short* __restrict__ Wt,  // 8 x 512 x 512 bf16 [e][o][i]
    const float* __restrict__ bias,         // 8 x 512 f32 [e][o]
    const float* __restrict__ wq,           // 65536 x 8 f32
    void* __restrict__ Out) {
  __shared__ __align__(16) char Lraw[114688];
  __shared__ __align__(16) float w_lds[8 * 256];     // [e][row] 8KB
  __shared__ __align__(16) float bias_lds[8 * 128];  // [e][col] 4KB

  const int tid = threadIdx.x;               // 0..511
  const int lane = tid & 63;
  const int wave = tid >> 6;                 // 0..7
  const int wr = wave >> 1, wc = wave & 1;   // 4M x 2N
  const int lhi = lane >> 4, llo = lane & 15;

  // XCD swizzle, mb-grouped: the 4 nb-blocks of one mb are adjacent on one
  // XCD -> concurrent A footprint per XCD = 8 tiles x 256KB = 2MB < 4MB L2.
  const int g = blockIdx.x;                  // 1024 blocks
  const int xcd = g & 7;
  const int sg = g >> 3;                     // 0..127
  const int nb = sg & 3;
  const int mb = xcd * 32 + (sg >> 2);       // 0..255
  const size_t row0 = (size_t)mb * 256;
  const int col0 = nb * 128;

  for (int i = tid; i < 2048; i += 512) {
    const int e = i >> 8, r = i & 255;
    w_lds[i] = wq[(row0 + r) * 8 + e];
  }
  for (int i = tid; i < 1024; i += 512) {
    const int e = i >> 7, r = i & 127;
    bias_lds[i] = bias[e * 512 + col0 + r];
  }
  __syncthreads();  // full drain: vmcnt bookkeeping starts at 0

  // staging geometry: 512 threads = 64 rows x 8 chunks(16B); XOR chunk swizzle
  const int srow = tid >> 3;                      // 0..63
  const int cgo = ((tid & 7) ^ (srow & 7)) << 4;  // swizzled global 16B chunk
  const char* Ag = (const char*)X + (row0 + srow) * 1024 + cgo;
  const char* Bg = (const char*)Wt + (size_t)(col0 + srow) * 1024 + cgo;
  char* const L = Lraw;

  // A tile: 256 rows x 128B -> 4 async rounds (rows srow+64j)
  auto stageA = [&](int aOff, int kta) {
    const char* ga = Ag + kta * 128;
    char* lp = L + aOff + tid * 16;
#pragma unroll
    for (int j = 0; j < 4; j++) async_ld16(ga + j * 65536, lp + j * 8192);
  };
  // B tile: 128 rows x 128B -> 2 async rounds
  auto stageB = [&](int bOff, int eb, int ktb) {
    const char* gb = Bg + (size_t)eb * 524288 + ktb * 128;
    char* lp = L + bOff + tid * 16;
    async_ld16(gb, lp);
    async_ld16(gb + 65536, lp + 8192);
  };

  int b0 = 65536, b1 = 81920, b2 = 98304;  // B triple-buffer byte offsets

  // prologue: A[0] (4 loads), B[e0,kt0] (2), B[e1,kt0] (2)
  stageA(0, 0);
  stageB(b0, 0, 0);
  stageB(b1, 1, 0);
  asm volatile("s_waitcnt vmcnt(2)" ::: "memory");  // A[0]+B[0] complete
  __builtin_amdgcn_s_barrier();

  const int rsw = llo & 7;                    // frag-read swizzle key
  const int slot0 = (lhi ^ rsw) << 4;         // k = 0..31
  const int slot1 = ((4 + lhi) ^ rsw) << 4;   // k = 32..63
  const int aRowB = (wr * 64 + llo) * 128;    // + fm*2048
  const int bRowB = (wc * 64 + llo) * 128;    // + fn*2048 (relative to b-buf)

  const f32x4 vzero = {0.f, 0.f, 0.f, 0.f};
  f32x4 C[4][4];
#pragma unroll
  for (int i = 0; i < 4; i++)
#pragma unroll
    for (int j = 0; j < 4; j++) C[i][j] = vzero;

#pragma unroll 1
  for (int kt = 0; kt < 8; kt++) {
    const int aOff = (kt & 1) * 32768;
    // A fragments for this kt -> registers (32 VGPR), reused by all 8 experts
    bf16x8 av[4][2];
#pragma unroll
    for (int fm = 0; fm < 4; fm++) {
      av[fm][0] = *(const bf16x8*)(L + aOff + aRowB + fm * 2048 + slot0);
      av[fm][1] = *(const bf16x8*)(L + aOff + aRowB + fm * 2048 + slot1);
    }

#pragma unroll
    for (int e = 0; e < 8; e++) {
      // ds_read this expert's B fragments
      bf16x8 bv[4][2];
#pragma unroll
      for (int fn = 0; fn < 4; fn++) {
        bv[fn][0] = *(const bf16x8*)(L + b0 + bRowB + fn * 2048 + slot0);
        bv[fn][1] = *(const bf16x8*)(L + b0 + bRowB + fn * 2048 + slot1);
      }
      // issue prefetches (order matters for vmcnt counting: B first, then A)
      if (e < 6) {
        stageB(b2, e + 2, kt);
      } else if (kt < 7) {
        stageB(b2, e - 6, kt + 1);
      }
      if (e == 4 && kt < 7) stageA(((kt + 1) & 1) * 32768, kt + 1);

      __builtin_amdgcn_s_barrier();
      asm volatile("s_waitcnt lgkmcnt(0)" ::: "memory");
      __builtin_amdgcn_s_setprio(1);
      f32x4 acc[4][4];
#pragma unroll
      for (int fm = 0; fm < 4; fm++)
#pragma unroll
        for (int fn = 0; fn < 4; fn++)
          acc[fm][fn] = __builtin_amdgcn_mfma_f32_16x16x32_bf16(
              av[fm][0], bv[fn][0], vzero, 0, 0, 0);
#pragma unroll
      for (int fm = 0; fm < 4; fm++)
#pragma unroll
        for (int fn = 0; fn < 4; fn++)
          acc[fm][fn] = __builtin_amdgcn_mfma_f32_16x16x32_bf16(
              av[fm][1], bv[fn][1], acc[fm][fn], 0, 0, 0);
      __builtin_amdgcn_s_setprio(0);

      // fold this expert's partial into C with per-row gate weight
#pragma unroll
      for (int fm = 0; fm < 4; fm++) {
        const f32x4 wv =
            *(const f32x4*)(w_lds + e * 256 + wr * 64 + fm * 16 + lhi * 4);
#pragma unroll
        for (int fn = 0; fn < 4; fn++)
#pragma unroll
          for (int r = 0; r < 4; r++) C[fm][fn][r] += wv[r] * acc[fm][fn][r];
      }

      // end-of-step wait: retire next B tile (and A at kt boundary).
      // outstanding after B[t+1]: 2 (B[t+2]) + 4 on the two steps after the
      // A-issue. Never drains to 0 until the tail.
      if ((e == 4 || e == 5) && kt < 7) {
        asm volatile("s_waitcnt vmcnt(6)" ::: "memory");
      } else if (kt == 7 && e >= 6) {
        asm volatile("s_waitcnt vmcnt(0)" ::: "memory");
      } else {
        asm volatile("s_waitcnt vmcnt(2)" ::: "memory");
      }
      __builtin_amdgcn_s_barrier();
      const int tmp = b0; b0 = b1; b1 = b2; b2 = tmp;  // rotate B buffers
    }
  }

  // bias: C += sum_e w[row,e] * b[e,col]  (once per block)
#pragma unroll
  for (int e = 0; e < 8; e++) {
    f32x4 wv[4];
#pragma unroll
    for (int fm = 0; fm < 4; fm++)
      wv[fm] = *(const f32x4*)(w_lds + e * 256 + wr * 64 + fm * 16 + lhi * 4);
#pragma unroll
    for (int fn = 0; fn < 4; fn++) {
      const float bb = bias_lds[e * 128 + wc * 64 + fn * 16 + llo];
#pragma unroll
      for (int fm = 0; fm < 4; fm++)
#pragma unroll
        for (int r = 0; r < 4; r++) C[fm][fn][r] += wv[fm][r] * bb;
    }
  }

  // epilogue: ELU + store (bf16 h or f32 final)
#pragma unroll
  for (int fm = 0; fm < 4; fm++)
#pragma unroll
    for (int fn = 0; fn < 4; fn++)
#pragma unroll
      for (int r = 0; r < 4; r++) {
        float v = C[fm][fn][r];
        if (ELU) v = elu_f(v);
        const size_t orow = row0 + wr * 64 + fm * 16 + lhi * 4 + r;
        const int ocol = col0 + wc * 64 + fn * 16 + llo;
        if (OUTBF)
          ((unsigned short*)Out)[orow * 512 + ocol] = f2bf(v);
        else
          ((float*)Out)[orow * 512 + ocol] = v;
      }
}

extern "C" void kernel_launch(void* const* d_in, const int* in_sizes, int n_in,
                              void* d_out, int out_size, void* d_ws,
                              size_t ws_size, hipStream_t stream) {
  (void)in_sizes; (void)n_in; (void)out_size; (void)ws_size;
  const float* z   = (const float*)d_in[0];
  const int*   idx = (const int*)d_in[1];
  const float* Wg1 = (const float*)d_in[2];
  const float* bg1 = (const float*)d_in[3];
  const float* Wg2 = (const float*)d_in[4];
  const float* bg2 = (const float*)d_in[5];
  const float* Wg3 = (const float*)d_in[6];
  const float* bg3 = (const float*)d_in[7];
  const float* W1  = (const float*)d_in[8];
  const float* b1  = (const float*)d_in[9];
  const float* W2  = (const float*)d_in[10];
  const float* b2  = (const float*)d_in[11];
  const float* W3  = (const float*)d_in[12];
  const float* b3  = (const float*)d_in[13];

  // workspace layout:
  //   [0,2M)      w gate logits f32
  //   [2M,66M)    zb  (z bf16)        -- layer2 output h2 aliases here
  //   [66M,130M)  h1 bf16
  //   [130M,142M) Wt: 3x8x512x512 bf16 [l][e][o][i]
  char* ws = (char*)d_ws;
  float* wq = (float*)ws;
  unsigned short* zb = (unsigned short*)(ws + (size_t)(2u << 20));
  unsigned short* h1 = (unsigned short*)(ws + (size_t)(66u << 20));
  unsigned short* Wt = (unsigned short*)(ws + (size_t)(130u << 20));
  unsigned short* h2 = zb;        // zb dead after layer1

  gating_mfma<<<dim3(512), dim3(256), 0, stream>>>(
      z, idx, Wg1, bg1, Wg2, bg2, Wg3, bg3, wq, zb);
  transpose_w<<<dim3(16, 16, 24), dim3(256), 0, stream>>>(W1, W2, W3, Wt);

  expert_layer<true, true><<<dim3(1024), dim3(512), 0, stream>>>(
      zb, Wt, b1, wq, (void*)h1);
  expert_layer<true, true><<<dim3(1024), dim3(512), 0, stream>>>(
      h1, Wt + (size_t)8 * 262144, b2, wq, (void*)h2);
  expert_layer<false, false><<<dim3(1024), dim3(512), 0, stream>>>(
      h2, Wt + (size_t)16 * 262144, b3, wq, d_out);
}

// Round 3
// 1177.819 us; speedup vs baseline: 9.5128x; 9.5128x over previous
//
#include <hip/hip_runtime.h>

#define B_ROWS 65536

typedef __attribute__((ext_vector_type(8))) __bf16 bf16x8;
typedef __attribute__((ext_vector_type(8))) _Float16 f16x8;
typedef __attribute__((ext_vector_type(4))) float f32x4;
typedef __attribute__((ext_vector_type(8))) unsigned short u16x8;

__device__ __forceinline__ unsigned short f2bf(float f) {
  unsigned int u = __float_as_uint(f);
  u += 0x7fffu + ((u >> 16) & 1u);   // RNE
  return (unsigned short)(u >> 16);
}

__device__ __forceinline__ float elu_f(float v) {
  return v > 0.f ? v : __expf(v) - 1.f;
}

__device__ __forceinline__ void async_ld16(const void* g, void* l) {
  __builtin_amdgcn_global_load_lds(
      (const __attribute__((address_space(1))) void*)g,
      (__attribute__((address_space(3))) void*)l, 16, 0, 0);
}

// ---------------- fused gating MLP (f16 MFMA, f32 acc) + z->bf16 convert ----
#define GP 136  // padded LDS row stride in f16 (272 B -> 2-way banks = free)

__global__ __launch_bounds__(256) void gating_mfma(
    const float* __restrict__ z, const int* __restrict__ idx,
    const float* __restrict__ Wg1, const float* __restrict__ bg1,
    const float* __restrict__ Wg2, const float* __restrict__ bg2,
    const float* __restrict__ Wg3, const float* __restrict__ bg3,
    float* __restrict__ wq, unsigned short* __restrict__ zb) {
  __shared__ _Float16 Ab[128 * GP];   // activations [row][k]
  __shared__ _Float16 Wb[128 * GP];   // W^T [n][k]
  __shared__ int idx_l[128];

  const int tid = threadIdx.x;
  const int lane = tid & 63, wave = tid >> 6;
  const int wr = wave >> 1, wc = wave & 1;
  const int lhi = lane >> 4, llo = lane & 15;
  const size_t row0 = (size_t)blockIdx.x * 128;

  if (tid < 128) idx_l[tid] = idx[tid];
  for (int i = tid; i < 16384; i += 256) {
    const int k = i >> 7, n = i & 127;
    Wb[n * GP + k] = (_Float16)Wg1[i];
  }
  {
    const float* zr = z + row0 * 512;
    unsigned short* zo = zb + row0 * 512;
    for (int i = tid; i < 8192; i += 256) {
      const size_t off = (size_t)i * 8;
      float4 a = *(const float4*)(zr + off);
      float4 b = *(const float4*)(zr + off + 4);
      u16x8 r;
      r[0] = f2bf(a.x); r[1] = f2bf(a.y); r[2] = f2bf(a.z); r[3] = f2bf(a.w);
      r[4] = f2bf(b.x); r[5] = f2bf(b.y); r[6] = f2bf(b.z); r[7] = f2bf(b.w);
      *(u16x8*)(zo + off) = r;
    }
  }
  __syncthreads();
  for (int i = tid; i < 16384; i += 256) {
    const int r = i >> 7, c = i & 127;
    Ab[r * GP + c] = (_Float16)z[(row0 + r) * 512 + idx_l[c]];
  }
  __syncthreads();

  const f32x4 vzero = {0.f, 0.f, 0.f, 0.f};

  // ---- layer 1 ----
  f32x4 C[4][4];
#pragma unroll
  for (int i = 0; i < 4; i++)
#pragma unroll
    for (int j = 0; j < 4; j++) C[i][j] = vzero;
#pragma unroll
  for (int ks = 0; ks < 4; ks++) {
    f16x8 av[4], bv[4];
#pragma unroll
    for (int fm = 0; fm < 4; fm++)
      av[fm] = *(const f16x8*)&Ab[(wr * 64 + fm * 16 + llo) * GP + ks * 32 + lhi * 8];
#pragma unroll
    for (int fn = 0; fn < 4; fn++)
      bv[fn] = *(const f16x8*)&Wb[(wc * 64 + fn * 16 + llo) * GP + ks * 32 + lhi * 8];
#pragma unroll
    for (int fm = 0; fm < 4; fm++)
#pragma unroll
      for (int fn = 0; fn < 4; fn++)
        C[fm][fn] = __builtin_amdgcn_mfma_f32_16x16x32_f16(av[fm], bv[fn], C[fm][fn], 0, 0, 0);
  }
  __syncthreads();
#pragma unroll
  for (int fm = 0; fm < 4; fm++)
#pragma unroll
    for (int fn = 0; fn < 4; fn++) {
      const int col = wc * 64 + fn * 16 + llo;
      const float bb = bg1[col];
#pragma unroll
      for (int r = 0; r < 4; r++) {
        const int row = wr * 64 + fm * 16 + lhi * 4 + r;
        Ab[row * GP + col] = (_Float16)elu_f(C[fm][fn][r] + bb);
      }
    }
  for (int i = tid; i < 16384; i += 256) {
    const int k = i >> 7, n = i & 127;
    Wb[n * GP + k] = (_Float16)Wg2[i];
  }
  __syncthreads();

  // ---- layer 2 ----
#pragma unroll
  for (int i = 0; i < 4; i++)
#pragma unroll
    for (int j = 0; j < 4; j++) C[i][j] = vzero;
#pragma unroll
  for (int ks = 0; ks < 4; ks++) {
    f16x8 av[4], bv[4];
#pragma unroll
    for (int fm = 0; fm < 4; fm++)
      av[fm] = *(const f16x8*)&Ab[(wr * 64 + fm * 16 + llo) * GP + ks * 32 + lhi * 8];
#pragma unroll
    for (int fn = 0; fn < 4; fn++)
      bv[fn] = *(const f16x8*)&Wb[(wc * 64 + fn * 16 + llo) * GP + ks * 32 + lhi * 8];
#pragma unroll
    for (int fm = 0; fm < 4; fm++)
#pragma unroll
      for (int fn = 0; fn < 4; fn++)
        C[fm][fn] = __builtin_amdgcn_mfma_f32_16x16x32_f16(av[fm], bv[fn], C[fm][fn], 0, 0, 0);
  }
  __syncthreads();
#pragma unroll
  for (int fm = 0; fm < 4; fm++)
#pragma unroll
    for (int fn = 0; fn < 4; fn++) {
      const int col = wc * 64 + fn * 16 + llo;
      const float bb = bg2[col];
#pragma unroll
      for (int r = 0; r < 4; r++) {
        const int row = wr * 64 + fm * 16 + lhi * 4 + r;
        Ab[row * GP + col] = (_Float16)elu_f(C[fm][fn][r] + bb);
      }
    }
  for (int i = tid; i < 2048; i += 256) {
    const int k = i >> 4, n = i & 15;
    Wb[n * GP + k] = (n < 8) ? (_Float16)Wg3[k * 8 + n] : (_Float16)0.f;
  }
  __syncthreads();

  // ---- layer 3 ----
  f32x4 C3[4];
#pragma unroll
  for (int i = 0; i < 4; i++) C3[i] = vzero;
#pragma unroll
  for (int ks = 0; ks < 4; ks++) {
    f16x8 av[4];
#pragma unroll
    for (int fm = 0; fm < 4; fm++)
      av[fm] = *(const f16x8*)&Ab[(wr * 64 + fm * 16 + llo) * GP + ks * 32 + lhi * 8];
    const f16x8 bv = *(const f16x8*)&Wb[llo * GP + ks * 32 + lhi * 8];
#pragma unroll
    for (int fm = 0; fm < 4; fm++)
      C3[fm] = __builtin_amdgcn_mfma_f32_16x16x32_f16(av[fm], bv, C3[fm], 0, 0, 0);
  }
  if (wc == 0 && llo < 8) {
    const float bb = bg3[llo];
#pragma unroll
    for (int fm = 0; fm < 4; fm++)
#pragma unroll
      for (int r = 0; r < 4; r++) {
        const size_t row = row0 + wr * 64 + fm * 16 + lhi * 4 + r;
        wq[row * 8 + llo] = C3[fm][r] + bb;
      }
  }
}

// ---------------- W[e][i][o] f32 -> Wt[e][o][i] bf16 (B^T layout) ----------
__global__ __launch_bounds__(256) void transpose_w(
    const float* __restrict__ W1, const float* __restrict__ W2,
    const float* __restrict__ W3, unsigned short* __restrict__ Wt) {
  __shared__ float t[32][33];
  const int le = blockIdx.z;  // layer*8 + e, 0..23
  const float* W = (le < 8) ? W1 : (le < 16) ? W2 : W3;
  const size_t eoff = (size_t)(le & 7) * 262144;
  unsigned short* O = Wt + (size_t)le * 262144;
  const int i0 = blockIdx.y * 32, o0 = blockIdx.x * 32;
  const int tx = threadIdx.x & 31, ty = threadIdx.x >> 5;
#pragma unroll
  for (int s = 0; s < 4; s++)
    t[ty + s * 8][tx] = W[eoff + (size_t)(i0 + ty + s * 8) * 512 + o0 + tx];
  __syncthreads();
#pragma unroll
  for (int s = 0; s < 4; s++)
    O[(size_t)(o0 + ty + s * 8) * 512 + i0 + tx] = f2bf(t[tx][ty + s * 8]);
}

// ---------------- soft-MoE expert layer: out = sum_e w_e*(X@W_e + b_e) -----
// BM=256 x BN=128 tile, BK=64, 512 threads (8 waves, 4Mx2N, each 64x64).
// LOOP-INTERCHANGED: kt outer, e inner.  C = sum_kt sum_e w_e*(A_kt @ B_e,kt)
//   - A-tile staged once per kt (32KB, double-buffered), its 8 MFMA frags
//     held in 32 VGPRs for all 8 expert steps -> A global traffic cut 8x and
//     steady-state LDS frag reads halved.
//   - B tiles (16KB) triple-buffered, prefetch depth 2, counted vmcnt:
//     steady vmcnt(2); vmcnt(6) on the two steps after the A-issue (e==4).
//   - setprio(1) around each 32-MFMA cluster; per-step f32 combine C += w*acc.
// REGISTER BUDGET (round-2 lesson): live set ~217 regs (C 64 + acc 64 +
// av 32 + bv 32 + addr). __launch_bounds__(512, *1*) -> 1 block/CU ->
// 2 waves/SIMD -> 256-reg cap. (512,2) meant 2 blocks/CU -> 128 cap ->
// ~16KB/thread scratch thrash (8.2 GB WRITE_SIZE, MfmaUtil 2.8%). e-loop is
// unroll-1 to keep cross-iteration pressure flat.
// LDS: A 2x32768 @0, B 3x16384 @65536 -> 114688 B (+w/bias 12KB).
template <bool ELU, bool OUTBF>
__global__ __launch_bounds__(512, 1) void expert_layer(
    const unsigned short* __restrict__ X,   // 65536 x 512 bf16
    const unsigned short* __restrict__ Wt,  // 8 x 512 x 512 bf16 [e][o][i]
    const float* __restrict__ bias,         // 8 x 512 f32 [e][o]
    const float* __restrict__ wq,           // 65536 x 8 f32
    void* __restrict__ Out) {
  __shared__ __align__(16) char Lraw[114688];
  __shared__ __align__(16) float w_lds[8 * 256];     // [e][row] 8KB
  __shared__ __align__(16) float bias_lds[8 * 128];  // [e][col] 4KB

  const int tid = threadIdx.x;               // 0..511
  const int lane = tid & 63;
  const int wave = tid >> 6;                 // 0..7
  const int wr = wave >> 1, wc = wave & 1;   // 4M x 2N
  const int lhi = lane >> 4, llo = lane & 15;

  // XCD swizzle, mb-grouped: the 4 nb-blocks of one mb are adjacent on one
  // XCD -> concurrent A footprint per XCD = 8 tiles x 256KB = 2MB < 4MB L2.
  const int g = blockIdx.x;                  // 1024 blocks
  const int xcd = g & 7;
  const int sg = g >> 3;                     // 0..127
  const int nb = sg & 3;
  const int mb = xcd * 32 + (sg >> 2);       // 0..255
  const size_t row0 = (size_t)mb * 256;
  const int col0 = nb * 128;

  for (int i = tid; i < 2048; i += 512) {
    const int e = i >> 8, r = i & 255;
    w_lds[i] = wq[(row0 + r) * 8 + e];
  }
  for (int i = tid; i < 1024; i += 512) {
    const int e = i >> 7, r = i & 127;
    bias_lds[i] = bias[e * 512 + col0 + r];
  }
  __syncthreads();  // full drain: vmcnt bookkeeping starts at 0

  // staging geometry: 512 threads = 64 rows x 8 chunks(16B); XOR chunk swizzle
  const int srow = tid >> 3;                      // 0..63
  const int cgo = ((tid & 7) ^ (srow & 7)) << 4;  // swizzled global 16B chunk
  const char* Ag = (const char*)X + (row0 + srow) * 1024 + cgo;
  const char* Bg = (const char*)Wt + (size_t)(col0 + srow) * 1024 + cgo;
  char* const L = Lraw;

  // A tile: 256 rows x 128B -> 4 async rounds (rows srow+64j)
  auto stageA = [&](int aOff, int kta) {
    const char* ga = Ag + kta * 128;
    char* lp = L + aOff + tid * 16;
#pragma unroll
    for (int j = 0; j < 4; j++) async_ld16(ga + j * 65536, lp + j * 8192);
  };
  // B tile: 128 rows x 128B -> 2 async rounds
  auto stageB = [&](int bOff, int eb, int ktb) {
    const char* gb = Bg + (size_t)eb * 524288 + ktb * 128;
    char* lp = L + bOff + tid * 16;
    async_ld16(gb, lp);
    async_ld16(gb + 65536, lp + 8192);
  };

  int b0 = 65536, b1 = 81920, b2 = 98304;  // B triple-buffer byte offsets

  // prologue: A[0] (4 loads), B[e0,kt0] (2), B[e1,kt0] (2)
  stageA(0, 0);
  stageB(b0, 0, 0);
  stageB(b1, 1, 0);
  asm volatile("s_waitcnt vmcnt(2)" ::: "memory");  // A[0]+B[0] complete
  __builtin_amdgcn_s_barrier();

  const int rsw = llo & 7;                    // frag-read swizzle key
  const int slot0 = (lhi ^ rsw) << 4;         // k = 0..31
  const int slot1 = ((4 + lhi) ^ rsw) << 4;   // k = 32..63
  const int aRowB = (wr * 64 + llo) * 128;    // + fm*2048
  const int bRowB = (wc * 64 + llo) * 128;    // + fn*2048 (relative to b-buf)

  const f32x4 vzero = {0.f, 0.f, 0.f, 0.f};
  f32x4 C[4][4];
#pragma unroll
  for (int i = 0; i < 4; i++)
#pragma unroll
    for (int j = 0; j < 4; j++) C[i][j] = vzero;

#pragma unroll 1
  for (int kt = 0; kt < 8; kt++) {
    const int aOff = (kt & 1) * 32768;
    // A fragments for this kt -> registers (32 VGPR), reused by all 8 experts
    bf16x8 av[4][2];
#pragma unroll
    for (int fm = 0; fm < 4; fm++) {
      av[fm][0] = *(const bf16x8*)(L + aOff + aRowB + fm * 2048 + slot0);
      av[fm][1] = *(const bf16x8*)(L + aOff + aRowB + fm * 2048 + slot1);
    }

#pragma unroll 1
    for (int e = 0; e < 8; e++) {
      // ds_read this expert's B fragments
      bf16x8 bv[4][2];
#pragma unroll
      for (int fn = 0; fn < 4; fn++) {
        bv[fn][0] = *(const bf16x8*)(L + b0 + bRowB + fn * 2048 + slot0);
        bv[fn][1] = *(const bf16x8*)(L + b0 + bRowB + fn * 2048 + slot1);
      }
      // issue prefetches (order matters for vmcnt counting: B first, then A)
      if (e < 6) {
        stageB(b2, e + 2, kt);
      } else if (kt < 7) {
        stageB(b2, e - 6, kt + 1);
      }
      if (e == 4 && kt < 7) stageA(((kt + 1) & 1) * 32768, kt + 1);

      __builtin_amdgcn_s_barrier();
      asm volatile("s_waitcnt lgkmcnt(0)" ::: "memory");
      __builtin_amdgcn_s_setprio(1);
      f32x4 acc[4][4];
#pragma unroll
      for (int fm = 0; fm < 4; fm++)
#pragma unroll
        for (int fn = 0; fn < 4; fn++)
          acc[fm][fn] = __builtin_amdgcn_mfma_f32_16x16x32_bf16(
              av[fm][0], bv[fn][0], vzero, 0, 0, 0);
#pragma unroll
      for (int fm = 0; fm < 4; fm++)
#pragma unroll
        for (int fn = 0; fn < 4; fn++)
          acc[fm][fn] = __builtin_amdgcn_mfma_f32_16x16x32_bf16(
              av[fm][1], bv[fn][1], acc[fm][fn], 0, 0, 0);
      __builtin_amdgcn_s_setprio(0);

      // fold this expert's partial into C with per-row gate weight
#pragma unroll
      for (int fm = 0; fm < 4; fm++) {
        const f32x4 wv =
            *(const f32x4*)(w_lds + e * 256 + wr * 64 + fm * 16 + lhi * 4);
#pragma unroll
        for (int fn = 0; fn < 4; fn++)
#pragma unroll
          for (int r = 0; r < 4; r++) C[fm][fn][r] += wv[r] * acc[fm][fn][r];
      }

      // end-of-step wait: retire next B tile (and A at kt boundary).
      // outstanding after B[t+1]: 2 (B[t+2]) + 4 on the two steps after the
      // A-issue. Never drains to 0 until the tail.
      if ((e == 4 || e == 5) && kt < 7) {
        asm volatile("s_waitcnt vmcnt(6)" ::: "memory");
      } else if (kt == 7 && e >= 6) {
        asm volatile("s_waitcnt vmcnt(0)" ::: "memory");
      } else {
        asm volatile("s_waitcnt vmcnt(2)" ::: "memory");
      }
      __builtin_amdgcn_s_barrier();
      const int tmp = b0; b0 = b1; b1 = b2; b2 = tmp;  // rotate B buffers
    }
  }

  // bias: C += sum_e w[row,e] * b[e,col]  (once per block)
#pragma unroll
  for (int e = 0; e < 8; e++) {
    f32x4 wv[4];
#pragma unroll
    for (int fm = 0; fm < 4; fm++)
      wv[fm] = *(const f32x4*)(w_lds + e * 256 + wr * 64 + fm * 16 + lhi * 4);
#pragma unroll
    for (int fn = 0; fn < 4; fn++) {
      const float bb = bias_lds[e * 128 + wc * 64 + fn * 16 + llo];
#pragma unroll
      for (int fm = 0; fm < 4; fm++)
#pragma unroll
        for (int r = 0; r < 4; r++) C[fm][fn][r] += wv[fm][r] * bb;
    }
  }

  // epilogue: ELU + store (bf16 h or f32 final)
#pragma unroll
  for (int fm = 0; fm < 4; fm++)
#pragma unroll
    for (int fn = 0; fn < 4; fn++)
#pragma unroll
      for (int r = 0; r < 4; r++) {
        float v = C[fm][fn][r];
        if (ELU) v = elu_f(v);
        const size_t orow = row0 + wr * 64 + fm * 16 + lhi * 4 + r;
        const int ocol = col0 + wc * 64 + fn * 16 + llo;
        if (OUTBF)
          ((unsigned short*)Out)[orow * 512 + ocol] = f2bf(v);
        else
          ((float*)Out)[orow * 512 + ocol] = v;
      }
}

extern "C" void kernel_launch(void* const* d_in, const int* in_sizes, int n_in,
                              void* d_out, int out_size, void* d_ws,
                              size_t ws_size, hipStream_t stream) {
  (void)in_sizes; (void)n_in; (void)out_size; (void)ws_size;
  const float* z   = (const float*)d_in[0];
  const int*   idx = (const int*)d_in[1];
  const float* Wg1 = (const float*)d_in[2];
  const float* bg1 = (const float*)d_in[3];
  const float* Wg2 = (const float*)d_in[4];
  const float* bg2 = (const float*)d_in[5];
  const float* Wg3 = (const float*)d_in[6];
  const float* bg3 = (const float*)d_in[7];
  const float* W1  = (const float*)d_in[8];
  const float* b1  = (const float*)d_in[9];
  const float* W2  = (const float*)d_in[10];
  const float* b2  = (const float*)d_in[11];
  const float* W3  = (const float*)d_in[12];
  const float* b3  = (const float*)d_in[13];

  // workspace layout:
  //   [0,2M)      w gate logits f32
  //   [2M,66M)    zb  (z bf16)        -- layer2 output h2 aliases here
  //   [66M,130M)  h1 bf16
  //   [130M,142M) Wt: 3x8x512x512 bf16 [l][e][o][i]
  char* ws = (char*)d_ws;
  float* wq = (float*)ws;
  unsigned short* zb = (unsigned short*)(ws + (size_t)(2u << 20));
  unsigned short* h1 = (unsigned short*)(ws + (size_t)(66u << 20));
  unsigned short* Wt = (unsigned short*)(ws + (size_t)(130u << 20));
  unsigned short* h2 = zb;        // zb dead after layer1

  gating_mfma<<<dim3(512), dim3(256), 0, stream>>>(
      z, idx, Wg1, bg1, Wg2, bg2, Wg3, bg3, wq, zb);
  transpose_w<<<dim3(16, 16, 24), dim3(256), 0, stream>>>(W1, W2, W3, Wt);

  expert_layer<true, true><<<dim3(1024), dim3(512), 0, stream>>>(
      zb, Wt, b1, wq, (void*)h1);
  expert_layer<true, true><<<dim3(1024), dim3(512), 0, stream>>>(
      h1, Wt + (size_t)8 * 262144, b2, wq, (void*)h2);
  expert_layer<false, false><<<dim3(1024), dim3(512), 0, stream>>>(
      h2, Wt + (size_t)16 * 262144, b3, wq, d_out);
}